// Round 1
// 311.439 us; speedup vs baseline: 1.1804x; 1.1804x over previous
//
#include <hip/hip_runtime.h>
#include <math.h>
#include <string.h>

// Problem constants (from reference)
#define BB 4
#define SS 1024
#define HH 32
#define GG 8       // kv heads
#define DD 128
#define NTOK (BB*SS)
#define NBLK 32
#define BLKSZ 256
#define CACHE_ELEMS ((size_t)NBLK*BLKSZ*GG*DD)   // 8.39M f32 per cache

typedef __attribute__((ext_vector_type(8)))  short  short8;   // 8 bf16 = 4 VGPRs (MFMA A/B operand)
typedef __attribute__((ext_vector_type(16))) float  floatx16; // MFMA C/D

union FragU { unsigned u[4]; uint4 u4; short8 s8; };

typedef __attribute__((address_space(3))) void  lds_void;
typedef __attribute__((address_space(1))) const void glb_void;

// round-to-nearest-even f32 -> bf16, packed pair (manual; used in prep path)
__device__ __forceinline__ unsigned pack_bf16x2(float a, float b) {
    unsigned ua = __builtin_bit_cast(unsigned, a);
    unsigned ub = __builtin_bit_cast(unsigned, b);
    ua = (ua + 0x7FFFu + ((ua >> 16) & 1u)) >> 16;
    ub = (ub + 0x7FFFu + ((ub >> 16) & 1u)) & 0xFFFF0000u;
    return ua | ub;
}

#if __has_builtin(__builtin_amdgcn_permlane32_swap)
#define HAVE_PL32 1
#endif

// single-instruction RNE packed f32->bf16 (same rounding as pack_bf16x2)
__device__ __forceinline__ unsigned cvt_pk_bf16(float lo, float hi) {
    unsigned r;
    asm("v_cvt_pk_bf16_f32 %0, %1, %2" : "=v"(r) : "v"(lo), "v"(hi));
    return r;
}

// cross-half (lane ^ 32) reduce via VALU permlane instead of DS shuffle
__device__ __forceinline__ float xhalf_max(float x) {
#ifdef HAVE_PL32
    unsigned u = __builtin_bit_cast(unsigned, x);
    auto r = __builtin_amdgcn_permlane32_swap(u, u, false, false);
    return fmaxf(__builtin_bit_cast(float, (unsigned)r[0]),
                 __builtin_bit_cast(float, (unsigned)r[1]));
#else
    return fmaxf(x, __shfl_xor(x, 32));
#endif
}
__device__ __forceinline__ float xhalf_add(float x) {
#ifdef HAVE_PL32
    unsigned u = __builtin_bit_cast(unsigned, x);
    auto r = __builtin_amdgcn_permlane32_swap(u, u, false, false);
    return __builtin_bit_cast(float, (unsigned)r[0]) +
           __builtin_bit_cast(float, (unsigned)r[1]);
#else
    return x + __shfl_xor(x, 32);
#endif
}

// ---------------- prepass: swizzle K/V to fragment layout + fused cache scatter ----------------
// K unit (16B) index: (((b*G + g)*32 + kt)*8 + s)*64 + lane
//   content: bf16 K[b*S + kt*32 + (lane&31)][g][s*16 + (lane>>5)*8 + 0..7]
// V unit index: (((b*G + g)*32 + kt)*8 + (t4*2 + s2))*64 + lane
//   content: bf16 pairs of V[b*S + kt*32 + s2*16 + (lane>>5)*8 + j][g][t4*32 + (lane&31)]
// Also writes the freshly-loaded f32 rows into the paged cache at slot_mapping
// positions (replaces the old standalone scatter_kernel: saves a 33.5 MB re-read).
// NOTE: must run AFTER copy_cache2 (scatter overwrites copied rows).
__global__ void prep_kv(const float* __restrict__ k, const float* __restrict__ v,
                        const int* __restrict__ slot_mapping,
                        uint4* __restrict__ ksw, uint4* __restrict__ vsw,
                        float* __restrict__ kco, float* __restrict__ vco) {
    __shared__ float lds[32 * 132];
    const int t = threadIdx.x;
    const int kt = blockIdx.x, gy = blockIdx.y, b = blockIdx.z;
    const int isv = gy >> 3, g = gy & 7;
    const float* sp = (isv ? v : k) + ((size_t)(b * SS + kt * 32) * GG + g) * DD;
    float* dco = isv ? vco : kco;
    #pragma unroll
    for (int i = 0; i < 4; ++i) {
        int u = t + 256 * i;                  // 1024 float4 units: row = u>>5, c4 = u&31
        int row = u >> 5, c4 = u & 31;
        float4 f = *(const float4*)(sp + (size_t)row * (GG * DD) + c4 * 4);
        float* lp = &lds[row * 132 + c4 * 4];
        lp[0] = f.x; lp[1] = f.y; lp[2] = f.z; lp[3] = f.w;
        int slot = slot_mapping[b * SS + kt * 32 + row];
        if ((unsigned)slot < (unsigned)(NBLK * BLKSZ))
            *(float4*)(dco + (size_t)slot * (GG * DD) + g * DD + c4 * 4) = f;
    }
    __syncthreads();
    const int lane = t & 63, hb = lane >> 5, l31 = lane & 31;
    const size_t tbase = ((size_t)(b * GG + g) * 32 + kt) * 8;
    if (!isv) {
        #pragma unroll
        for (int i = 0; i < 2; ++i) {
            int s = (t >> 6) + 4 * i;             // s in 0..7
            const float* lp = &lds[l31 * 132 + s * 16 + hb * 8];
            uint4 o;
            o.x = pack_bf16x2(lp[0], lp[1]); o.y = pack_bf16x2(lp[2], lp[3]);
            o.z = pack_bf16x2(lp[4], lp[5]); o.w = pack_bf16x2(lp[6], lp[7]);
            ksw[(tbase + s) * 64 + lane] = o;
        }
    } else {
        #pragma unroll
        for (int i = 0; i < 2; ++i) {
            int f8 = (t >> 6) + 4 * i;            // t4*2 + s2, 0..7
            int t4 = f8 >> 1, s2 = f8 & 1;
            int keyb = s2 * 16 + hb * 8;
            int d = t4 * 32 + l31;
            uint4 o;
            o.x = pack_bf16x2(lds[(keyb + 0) * 132 + d], lds[(keyb + 1) * 132 + d]);
            o.y = pack_bf16x2(lds[(keyb + 2) * 132 + d], lds[(keyb + 3) * 132 + d]);
            o.z = pack_bf16x2(lds[(keyb + 4) * 132 + d], lds[(keyb + 5) * 132 + d]);
            o.w = pack_bf16x2(lds[(keyb + 6) * 132 + d], lds[(keyb + 7) * 132 + d]);
            vsw[(tbase + f8) * 64 + lane] = o;
        }
    }
}

// ---------------- cache copy (both caches, one launch) ----------------
__global__ void copy_cache2(const float4* __restrict__ s0, const float4* __restrict__ s1,
                            float4* __restrict__ d0, float4* __restrict__ d1) {
    const size_t half = CACHE_ELEMS / 4;
    size_t i = (size_t)blockIdx.x * 256 + threadIdx.x;
    if (i < half) d0[i] = s0[i];
    else          d1[i - half] = s1[i - half];
}

// ---------------- fused causal GQA flash attention ----------------
// 1D grid of 512 blocks, each = 4 waves = 4 q-heads of one kv group.
// Balance: block with pair-index p processes q-tiles {31-p, p} sequentially ->
//   every block does exactly 33 kt-iterations (no causal-triangle tail drain).
// L2 locality: wg%8 = XCD (round-robin dispatch); each XCD owns 4 (b,g) pairs,
//   so its K/V swizzled working set is 2 MB < 4 MB L2 -> prefetch is L2-hit.
// Softmax: raw-score max tree, permlane32_swap cross-half ops (no DS shuffles),
//   defer-max (THR=8 in exp2 domain -> rescale only fires at kt=0),
//   v_cvt_pk_bf16_f32 for P->bf16 packing.
__global__ __launch_bounds__(256, 2)
void attn_kernel(const float* __restrict__ q,
                 const uint4* __restrict__ ksw,
                 const uint4* __restrict__ vsw,
                 float* __restrict__ out, float sc2 /* bf16(1/sqrt(D)) * log2(e) */) {
    __shared__ uint4 sm[2][16][64];               // [buf][row: 0-7 K, 8-15 V][lane], 32 KB
    const int lane = threadIdx.x & 63;
    const int wave = threadIdx.x >> 6;
    const int l31  = lane & 31;
    const int hb   = lane >> 5;

    const int wg  = blockIdx.x;                   // 0..511
    const int xcd = wg & 7;                       // round-robin XCD assumption
    const int sl  = wg >> 3;                      // 0..63 within XCD
    const int bg  = xcd * 4 + (sl >> 4);          // 4 (b,g) pairs per XCD
    const int pr  = sl & 15;                      // pair index 0..15
    const int b   = bg >> 3, g = bg & 7;
    const int h   = g * 4 + wave;
    const int tb  = b * SS;

    const uint4* kpl = ksw + (size_t)bg * (32 * 8 * 64);
    const uint4* vpl = vsw + (size_t)bg * (32 * 8 * 64);

    #pragma unroll 1
    for (int half = 0; half < 2; ++half) {
        const int qt = half ? pr : (31 - pr);     // long tile first, then short: 33 iters total
        const int q0 = qt * 32;

        // stage tile 0 into buffer 0: wave w stages K rows {2w,2w+1} and V rows {2w,2w+1}
        #pragma unroll
        for (int i = 0; i < 2; ++i) {
            int row = wave * 2 + i;
            __builtin_amdgcn_global_load_lds((glb_void*)(kpl + row * 64 + lane),
                                             (lds_void*)(&sm[0][row][0]),     16, 0, 0);
            __builtin_amdgcn_global_load_lds((glb_void*)(vpl + row * 64 + lane),
                                             (lds_void*)(&sm[0][8 + row][0]), 16, 0, 0);
        }

        // Q fragments (B operand of S^T): lane holds Q[q=l31][d = 16s + 8hb + j]
        short8 qf[8];
        const float* qp = q + ((size_t)(tb + q0 + l31) * HH + h) * DD;
        #pragma unroll
        for (int s = 0; s < 8; ++s) {
            int d0 = s * 16 + hb * 8;
            float4 f0 = *(const float4*)(qp + d0);
            float4 f1 = *(const float4*)(qp + d0 + 4);
            FragU fr;
            fr.u[0] = pack_bf16x2(f0.x, f0.y); fr.u[1] = pack_bf16x2(f0.z, f0.w);
            fr.u[2] = pack_bf16x2(f1.x, f1.y); fr.u[3] = pack_bf16x2(f1.z, f1.w);
            qf[s] = fr.s8;
        }

        floatx16 oacc[4] = {};            // O^T: 4 d-tiles of 32, col q = l31
        float m = -__builtin_inff(), l = 0.f;

        __syncthreads();                  // tile 0 resident

        for (int kt = 0; kt <= qt; ++kt) {
            const int cur = kt & 1;
            if (kt < qt) {                // prefetch tile kt+1 into the other buffer
                const uint4* gk = kpl + (kt + 1) * 512;
                const uint4* gv = vpl + (kt + 1) * 512;
                #pragma unroll
                for (int i = 0; i < 2; ++i) {
                    int row = wave * 2 + i;
                    __builtin_amdgcn_global_load_lds((glb_void*)(gk + row * 64 + lane),
                                                     (lds_void*)(&sm[cur ^ 1][row][0]),     16, 0, 0);
                    __builtin_amdgcn_global_load_lds((glb_void*)(gv + row * 64 + lane),
                                                     (lds_void*)(&sm[cur ^ 1][8 + row][0]), 16, 0, 0);
                }
            }
            // S^T tile: A = K (m=key, k=d chunk), B = Q^T — single accumulator chain
            floatx16 st = {};
            __builtin_amdgcn_s_setprio(1);
            #pragma unroll
            for (int s = 0; s < 8; ++s) {
                FragU ka; ka.u4 = sm[cur][s][lane];
                st = __builtin_amdgcn_mfma_f32_32x32x16_bf16(ka.s8, qf[s], st, 0, 0, 0);
            }
            __builtin_amdgcn_s_setprio(0);

            // raw scores (scale folded into the exp2 fma below); causal mask on last tile
            float e[16];
            #pragma unroll
            for (int r = 0; r < 16; ++r) {
                float val = st[r];
                if (kt == qt) {
                    int row = (r & 3) + 8 * (r >> 2) + 4 * hb; // key_local
                    if (row > l31) val = -__builtin_inff();
                }
                e[r] = val;
            }
            float trm[8];
            #pragma unroll
            for (int i = 0; i < 8; ++i) trm[i] = fmaxf(e[i], e[i + 8]);
            #pragma unroll
            for (int i = 0; i < 4; ++i) trm[i] = fmaxf(trm[i], trm[i + 4]);
            float tmax = fmaxf(fmaxf(trm[0], trm[2]), fmaxf(trm[1], trm[3]));
            tmax = xhalf_max(tmax) * sc2;          // scaled (exp2) domain

            // defer-max: skip rescale unless max moved by > 8 (p bounded by 2^8)
            if (__any(tmax > m + 8.f)) {
                const float mnew  = fmaxf(m, tmax);
                const float alpha = exp2f(m - mnew);
                #pragma unroll
                for (int t = 0; t < 4; ++t)
                    #pragma unroll
                    for (int r = 0; r < 16; ++r) oacc[t][r] *= alpha;
                l *= alpha;
                m = mnew;
            }

            float p_[16];
            #pragma unroll
            for (int r = 0; r < 16; ++r) p_[r] = exp2f(fmaf(e[r], sc2, -m));
            float sr[8];
            #pragma unroll
            for (int i = 0; i < 8; ++i) sr[i] = p_[i] + p_[i + 8];
            #pragma unroll
            for (int i = 0; i < 4; ++i) sr[i] += sr[i + 4];
            float psum = (sr[0] + sr[1]) + (sr[2] + sr[3]);
            l += xhalf_add(psum);

            // P -> bf16 pairs (single-instruction packed cvt, RNE)
            unsigned pk[8];
            #pragma unroll
            for (int u2 = 0; u2 < 8; ++u2) pk[u2] = cvt_pk_bf16(p_[2 * u2], p_[2 * u2 + 1]);

            // O^T += V^T * P^T  (two k-steps of 16 keys, 4 d-tiles)
            __builtin_amdgcn_s_setprio(1);
            #pragma unroll
            for (int s2 = 0; s2 < 2; ++s2) {
                FragU pf;
#ifdef HAVE_PL32
                // permlane32_swap(a=pk[4s2+i], b=pk[4s2+2+i]):
                //   r0 = lane<32 ? a[lane] : b[lane-32]  == pf.u[i]   for both halves
                //   r1 = lane<32 ? a[lane+32] : b[lane]  == pf.u[2+i] for both halves
                auto ra = __builtin_amdgcn_permlane32_swap(pk[4 * s2],     pk[4 * s2 + 2], false, false);
                auto rb = __builtin_amdgcn_permlane32_swap(pk[4 * s2 + 1], pk[4 * s2 + 3], false, false);
                pf.u[0] = (unsigned)ra[0]; pf.u[1] = (unsigned)rb[0];
                pf.u[2] = (unsigned)ra[1]; pf.u[3] = (unsigned)rb[1];
#else
                unsigned px0 = (unsigned)__shfl_xor((int)pk[4 * s2],     32);
                unsigned px1 = (unsigned)__shfl_xor((int)pk[4 * s2 + 1], 32);
                unsigned px2 = (unsigned)__shfl_xor((int)pk[4 * s2 + 2], 32);
                unsigned px3 = (unsigned)__shfl_xor((int)pk[4 * s2 + 3], 32);
                if (hb == 0) { pf.u[0] = pk[4*s2];   pf.u[1] = pk[4*s2+1]; pf.u[2] = px0; pf.u[3] = px1; }
                else         { pf.u[0] = px2; pf.u[1] = px3; pf.u[2] = pk[4*s2+2]; pf.u[3] = pk[4*s2+3]; }
#endif
                #pragma unroll
                for (int t = 0; t < 4; ++t) {
                    FragU vf; vf.u4 = sm[cur][8 + t * 2 + s2][lane];
                    oacc[t] = __builtin_amdgcn_mfma_f32_32x32x16_bf16(vf.s8, pf.s8, oacc[t], 0, 0, 0);
                }
            }
            __builtin_amdgcn_s_setprio(0);
            __syncthreads();   // all waves done with sm[cur]; prefetch into sm[cur^1] drained
        }

        // epilogue: normalize (state and O^T both keyed by q = l31 -> pure per-lane) and store
        const float inv_l = 1.f / l;
        float* op = out + ((size_t)(tb + q0 + l31) * HH + h) * DD;
        #pragma unroll
        for (int t = 0; t < 4; ++t) {
            #pragma unroll
            for (int grp = 0; grp < 4; ++grp) {
                float4 o4;
                o4.x = oacc[t][grp * 4 + 0] * inv_l; o4.y = oacc[t][grp * 4 + 1] * inv_l;
                o4.z = oacc[t][grp * 4 + 2] * inv_l; o4.w = oacc[t][grp * 4 + 3] * inv_l;
                *(float4*)(op + t * 32 + grp * 8 + hb * 4) = o4;  // d = 32t + 8grp + 4hb + 0..3
            }
        }
        // next half stages into sm[0]; safe: last loop iteration ended with __syncthreads
    }
}

extern "C" void kernel_launch(void* const* d_in, const int* in_sizes, int n_in,
                              void* d_out, int out_size, void* d_ws, size_t ws_size,
                              hipStream_t stream) {
    const float* q     = (const float*)d_in[0];
    const float* k     = (const float*)d_in[1];
    const float* v     = (const float*)d_in[2];
    const float* kc_in = (const float*)d_in[3];
    const float* vc_in = (const float*)d_in[4];
    const int*   slot  = (const int*)d_in[5];

    float* o_out  = (float*)d_out;                               // [4096][4096]
    float* kc_out = o_out + (size_t)NTOK * HH * DD;              // [32][256][8][128]
    float* vc_out = kc_out + CACHE_ELEMS;

    uint4* ksw = (uint4*)d_ws;                                   // 8.4 MB
    uint4* vsw = ksw + (size_t)BB * GG * 32 * 8 * 64;            // 8.4 MB

    // scale = f32(bf16(1/sqrt(D))), folded with log2(e) for exp2-domain softmax
    float sc = 1.0f / sqrtf((float)DD);
    unsigned u; memcpy(&u, &sc, 4);
    u = (u + 0x7FFFu + ((u >> 16) & 1u)) & 0xFFFF0000u;
    memcpy(&sc, &u, 4);
    const float sc2 = sc * 1.44269504088896340736f;

    // copy must precede prep_kv (its fused scatter overwrites copied rows)
    copy_cache2<<<(int)(CACHE_ELEMS / 4 / 256) * 2, 256, 0, stream>>>(
        (const float4*)kc_in, (const float4*)vc_in, (float4*)kc_out, (float4*)vc_out);
    prep_kv<<<dim3(32, GG * 2, BB), 256, 0, stream>>>(k, v, slot, ksw, vsw, kc_out, vc_out);
    attn_kernel<<<512, 256, 0, stream>>>(q, ksw, vsw, o_out, sc2);
}